// Round 7
// baseline (264.335 us; speedup 1.0000x reference)
//
#include <hip/hip_runtime.h>
#include <hip/hip_bf16.h>

// PLRNN step: out = A*z + relu(z - rowmean(z)) @ W^T + h,  A=diag(AW), W=AW-diag
// Rewritten: out = (z_act @ AW^T) + [A*min(z,mu) + h]   (exact identity)
// Round 10: same BM=32 tile / sA+sC clean-traffic design (r3/r9), but the
// block is 1024 threads = 16 waves (each wave: 32x32 tile, 2Mx2N frags).
// Diagnosis from r9: latency-bound, all pipes <35%, occupancy capped at
// 16 waves/CU (2 blocks x 8 waves, LDS-bound). 16-wave blocks keep LDS at
// 66.5KB -> still 2 blocks/CU but 32 waves/CU = 100% occupancy cap.
// VGPR must stay <=64 for 8 waves/SIMD: __launch_bounds__(1024, 8).

#define DZV 512
#define BM 32
#define LDA 520   // LDS row stride (shorts): 1040 B, 16B-aligned, non-pow2 bank stride

typedef __attribute__((ext_vector_type(8))) short short8;  // 8 bf16 = 4 VGPRs
typedef __attribute__((ext_vector_type(4))) float f32x4;   // MFMA C/D frag

__device__ __forceinline__ unsigned short f2bf(float x) {
  __hip_bfloat16 b = __float2bfloat16(x);
  return __builtin_bit_cast(unsigned short, b);
}
__device__ __forceinline__ float bf2f(unsigned short u) {
  return __builtin_bit_cast(float, (unsigned int)u << 16);
}

// Prep: pack AW (fp32) into bf16 MFMA-B-fragment order + extract diagonal.
// Frag idx=(T*16+s)*64+L holds 8 bf16 = AW[T*16+(L&15)][s*32+(L>>4)*8 + j]:
// a wave's B-frag load (lane L reads idx base+L) is 1KB contiguous, L2-hot.
__global__ void pack_b(const float* __restrict__ AW, unsigned short* __restrict__ AWp,
                       float* __restrict__ Adiag) {
  int idx = blockIdx.x * 256 + threadIdx.x;     // 0..32767
  int L = idx & 63, s = (idx >> 6) & 15, T = idx >> 10;
  int n = T * 16 + (L & 15);
  int k = s * 32 + (L >> 4) * 8;
  const float4* src = (const float4*)(AW + n * DZV + k);
  float4 a = src[0], b = src[1];
  union { unsigned short u[8]; short8 v; } p;
  p.u[0] = f2bf(a.x); p.u[1] = f2bf(a.y); p.u[2] = f2bf(a.z); p.u[3] = f2bf(a.w);
  p.u[4] = f2bf(b.x); p.u[5] = f2bf(b.y); p.u[6] = f2bf(b.z); p.u[7] = f2bf(b.w);
  *(short8*)(AWp + idx * 8) = p.v;
  if (idx < DZV) Adiag[idx] = AW[idx * (DZV + 1)];
}

__global__ __launch_bounds__(1024, 8) void plrnn_step(
    const float* __restrict__ z, const float* __restrict__ h,
    const unsigned short* __restrict__ AWp, const float* __restrict__ Adiag,
    float* __restrict__ out)
{
  __shared__ unsigned short sA[BM * LDA];  // z_act panel (bf16), 33.3 KB
  __shared__ unsigned short sC[BM * LDA];  // corr = A*min(z,mu)+h (bf16), 33.3 KB

  const int t = threadIdx.x;
  const int row0 = blockIdx.x * BM;

  const int lane = t & 63;
  const int wave = t >> 6;           // 16 waves; each owns 32 output cols
  const int lr   = lane & 15;
  const int quad = lane >> 4;
  const int nbase = wave * 32;

  // B frag base pointers: N-tiles wave*2+nt (packed global, 1KB per frag-load)
  const unsigned short* bb[2];
  #pragma unroll
  for (int nt = 0; nt < 2; ++nt)
    bb[nt] = AWp + (((wave * 2 + nt) * 16) * 64 + lane) * 8;

  // Pre-phase-1 B prefetch for s=0: flies under the z loads + barrier.
  short8 bf[2][2];
  #pragma unroll
  for (int nt = 0; nt < 2; ++nt)
    bf[0][nt] = *(const short8*)(bb[nt]);

  // ---- Phase 1: single coalesced pass over z; mean, relu->sA, corr->sC.
  //      1024 threads: 32 threads per row, 4 float4 (16 floats) each. ----
  {
    const int r = t >> 5;          // 0..31, 32 consecutive threads per row
    const int c = t & 31;
    const float4* zr = (const float4*)(z + (row0 + r) * DZV);
    float4 v[4];
    float s = 0.f;
    #pragma unroll
    for (int i = 0; i < 4; ++i) {
      v[i] = zr[c + i * 32];                   // coalesced 512B runs
      s += (v[i].x + v[i].y) + (v[i].z + v[i].w);
    }
    s += __shfl_xor(s, 1);
    s += __shfl_xor(s, 2);
    s += __shfl_xor(s, 4);
    s += __shfl_xor(s, 8);
    s += __shfl_xor(s, 16);        // reduce over the 32-lane half-wave = one row
    const float mu = s * (1.0f / 512.0f);
    #pragma unroll
    for (int i = 0; i < 4; ++i) {
      const int c4 = c + i * 32;               // float4 column index
      float4 Ad = ((const float4*)Adiag)[c4];  // L1-hot, 2KB shared
      float4 hv = ((const float4*)h)[c4];
      union { unsigned short u[4]; ushort4 v4; } pa, pc;
      pa.u[0] = f2bf(fmaxf(v[i].x - mu, 0.f));
      pa.u[1] = f2bf(fmaxf(v[i].y - mu, 0.f));
      pa.u[2] = f2bf(fmaxf(v[i].z - mu, 0.f));
      pa.u[3] = f2bf(fmaxf(v[i].w - mu, 0.f));
      pc.u[0] = f2bf(Ad.x * fminf(v[i].x, mu) + hv.x);
      pc.u[1] = f2bf(Ad.y * fminf(v[i].y, mu) + hv.y);
      pc.u[2] = f2bf(Ad.z * fminf(v[i].z, mu) + hv.z);
      pc.u[3] = f2bf(Ad.w * fminf(v[i].w, mu) + hv.w);
      *(ushort4*)&sA[r * LDA + c4 * 4] = pa.v4;
      *(ushort4*)&sC[r * LDA + c4 * 4] = pc.v4;
    }
  }

  __syncthreads();   // only barrier; K-loop below is barrier-free

  // ---- Phase 2: GEMM, 2M x 2N frags per wave (32x32 tile); A and B both
  //      register-double-buffered; latency hiding mainly via 8 waves/SIMD. ----
  const unsigned short* a0 = &sA[(lr) * LDA + quad * 8];
  const unsigned short* a1 = &sA[(16 + lr) * LDA + quad * 8];

  short8 af[2][2];
  af[0][0] = *(const short8*)(a0);
  af[0][1] = *(const short8*)(a1);

  f32x4 acc[2][2];
  #pragma unroll
  for (int mt = 0; mt < 2; ++mt)
    #pragma unroll
    for (int nt = 0; nt < 2; ++nt)
      acc[mt][nt] = (f32x4){0.f, 0.f, 0.f, 0.f};

  #pragma unroll
  for (int s = 0; s < 16; ++s) {     // k = s*32
    const int cur = s & 1, nxt = cur ^ 1;
    if (s < 15) {                    // prefetch s+1 BEFORE computing s
      #pragma unroll
      for (int nt = 0; nt < 2; ++nt)
        bf[nxt][nt] = *(const short8*)(bb[nt] + (s + 1) * 512);  // L2, dwordx4
      af[nxt][0] = *(const short8*)(a0 + (s + 1) * 32);          // ds_read_b128
      af[nxt][1] = *(const short8*)(a1 + (s + 1) * 32);
    }
    #pragma unroll
    for (int nt = 0; nt < 2; ++nt) {
      acc[0][nt] = __builtin_amdgcn_mfma_f32_16x16x32_bf16(af[cur][0], bf[cur][nt], acc[0][nt], 0, 0, 0);
      acc[1][nt] = __builtin_amdgcn_mfma_f32_16x16x32_bf16(af[cur][1], bf[cur][nt], acc[1][nt], 0, 0, 0);
    }
  }

  // ---- Epilogue: out = acc + corr; nt innermost -> 2 adjacent 64B segments
  // per row back-to-back (waves tile the rest of the line); L2 merges. ----
  #pragma unroll
  for (int mt = 0; mt < 2; ++mt) {
    #pragma unroll
    for (int r = 0; r < 4; ++r) {
      const int lm = mt * 16 + quad * 4 + r;   // C/D layout: row = quad*4 + reg
      float corr[2];
      #pragma unroll
      for (int nt = 0; nt < 2; ++nt)
        corr[nt] = bf2f(sC[lm * LDA + nbase + nt * 16 + lr]);
      float* orow = out + (row0 + lm) * DZV + nbase + lr;
      #pragma unroll
      for (int nt = 0; nt < 2; ++nt)
        orow[nt * 16] = acc[mt][nt][r] + corr[nt];
    }
  }
}

extern "C" void kernel_launch(void* const* d_in, const int* in_sizes, int n_in,
                              void* d_out, int out_size, void* d_ws, size_t ws_size,
                              hipStream_t stream) {
  const float* z  = (const float*)d_in[0];
  const float* AW = (const float*)d_in[1];
  const float* h  = (const float*)d_in[2];
  float* out = (float*)d_out;
  unsigned short* AWp = (unsigned short*)d_ws;                     // 512 KB packed bf16
  float* Adiag = (float*)((char*)d_ws + DZV * DZV * sizeof(unsigned short)); // 2 KB

  pack_b<<<128, 256, 0, stream>>>(AW, AWp, Adiag);
  plrnn_step<<<65536 / BM, 1024, 0, stream>>>(z, h, AWp, Adiag, out);
}